// Round 19
// baseline (327.521 us; speedup 1.0000x reference)
//
#include <hip/hip_runtime.h>
#include <hip/hip_bf16.h>
#include <hip/hip_cooperative_groups.h>

namespace cg = cooperative_groups;

// GAT. 4-launch pipeline:
//  1) k_csr (COOPERATIVE, grid.sync between phases):
//       P0: dst bucket histograms || W fp32->bf16 || zero pooled
//       P1: wave-parallel 2D scan of block histograms (1 wave/bucket)
//       P2: scatter edges into bucket runs (LDS cursors, in-block base scan)
//       P3: per-bucket counting sort -> rowptr + csr
//  2) k_lin: h = x@W^T via bf16 MFMA + fused att coeffs
//  3) k_agg: wave per dst, scalarized broadcasts (v_readlane -> SGPR),
//     coalesced 256B row gathers, zero DS in hot loop, fused graph pooling
//  4) k_fcstat: BN stats recomputed per block (G-way parallel) + FC
// H=2 x C=64.  Softmax max-shift skipped (|e| small, exp safe in fp32).
// Lessons: shfl under divergence = poison (R7); s_load in DS loops = lgkmcnt
// drains (R11); split-lane atomics = write amplification (R10); per-bucket
// global atomic cursors = contention (R4); single-block serialization of
// parallel work = latency disaster (R14, R17); launch gaps -> coop fusion.

#define BKT_SHIFT 8              // 256 nodes per bucket
#define BKT_MASK  255
#define BKT_CAP   14336          // LDS staging records in bsort phase (56 KB)
#define BIN_TILE  4096           // edges per block in hist/bin

typedef __attribute__((ext_vector_type(8))) short bf16x8;
typedef __attribute__((ext_vector_type(4))) float f32x4;

static __device__ __forceinline__ float lo16(unsigned int u) {
    union { unsigned int i; float f; } c; c.i = u << 16; return c.f;
}
static __device__ __forceinline__ float hi16(unsigned int u) {
    union { unsigned int i; float f; } c; c.i = u & 0xffff0000u; return c.f;
}
static __device__ __forceinline__ unsigned short f2bf(float f) {
    unsigned int b = __builtin_bit_cast(unsigned int, f);
    return (unsigned short)((b >> 16) + ((b >> 15) & 1));
}
static __device__ __forceinline__ float rlane_f(float x, int l) {
    return __builtin_bit_cast(float, __builtin_amdgcn_readlane(__builtin_bit_cast(int, x), l));
}

// =================== launch 1: cooperative CSR build ===================
// Shared memory plan (62472 B, same footprint as the proven k_bsort):
//   bsort: lout[0:14336] | hist +14336 | sc +14592 | rp +14848 | lc +15104 |
//          part +15360 | bb/be +15616
//   bin:   gb[0:1024] | cnt[1024:2048] | part[2048:2304]
//   hist:  cnt[0:1024]
__global__ __launch_bounds__(256) void k_csr(const int* __restrict__ ei, int E,
                                             int* __restrict__ blkhist, int NB,
                                             const float* __restrict__ w,
                                             unsigned short* __restrict__ wb,
                                             float* __restrict__ pooled,
                                             long long npool, int nbin,
                                             int* __restrict__ tot,
                                             int* __restrict__ rowptr,
                                             int* __restrict__ csr,
                                             unsigned int* __restrict__ stage,
                                             int N) {
    __shared__ int smem[15618];
    cg::grid_group grid = cg::this_grid();
    const int t = threadIdx.x;
    const int nblk = gridDim.x;

    // ---------------- P0: histogram | wcvt | zero pooled ----------------
    for (int vb = blockIdx.x; vb < nbin + 128; vb += nblk) {
        if (vb < nbin) {
            int* cnt = smem;
            for (int i = t; i < 1024; i += 256) cnt[i] = 0;
            __syncthreads();
            int base = vb * BIN_TILE;
            int end = min(base + BIN_TILE, E);
            for (int i = base + t; i < end; i += 256)
                atomicAdd(&cnt[ei[E + i] >> BKT_SHIFT], 1);
            __syncthreads();
            int* row = blkhist + (size_t)vb * NB;
            for (int b = t; b < NB; b += 256) row[b] = cnt[b];
            __syncthreads();
        } else if (vb < nbin + 64) {
            int i = (vb - nbin) * 256 + t;       // 64*256 = 16384 = 128*128
            wb[i] = f2bf(w[i]);
        } else {
            long long i = (long long)(vb - nbin - 64) * 256 + t;
            for (; i < npool; i += 64 * 256) pooled[i] = 0.f;
        }
    }
    grid.sync();

    // ---------------- P1: scanA (1 wave per bucket) ----------------
    for (int vb = blockIdx.x; vb < (NB + 3) / 4; vb += nblk) {
        int b = vb * 4 + (t >> 6);
        int lane = t & 63;
        if (b < NB) {
            int run = 0;
            for (int blk0 = 0; blk0 < nbin; blk0 += 64) {
                int idx = blk0 + lane;
                int v = (idx < nbin) ? blkhist[(size_t)idx * NB + b] : 0;
                int inc = v;
#pragma unroll
                for (int off = 1; off < 64; off <<= 1) {
                    int u = __shfl_up(inc, off);
                    if (lane >= off) inc += u;
                }
                if (idx < nbin) blkhist[(size_t)idx * NB + b] = run + (inc - v);
                run += __shfl(inc, 63);
            }
            if (lane == 0) tot[b] = run;
        }
    }
    grid.sync();

    // ---------------- P2: bin (scatter into bucket runs) ----------------
    for (int vb = blockIdx.x; vb < nbin; vb += nblk) {
        int* gb   = smem;
        int* cnt  = smem + 1024;
        int* part = smem + 2048;
        const int* row = blkhist + (size_t)vb * NB;
        int vals[4]; int s0 = 0;
#pragma unroll
        for (int k = 0; k < 4; ++k) {
            int b2 = t * 4 + k;
            vals[k] = (b2 < NB) ? tot[b2] : 0;
            s0 += vals[k];
        }
        part[t] = s0;
        __syncthreads();
        for (int off = 1; off < 256; off <<= 1) {
            int u = (t >= off) ? part[t - off] : 0;
            __syncthreads();
            part[t] += u;
            __syncthreads();
        }
        int base = part[t] - s0;
#pragma unroll
        for (int k = 0; k < 4; ++k) {
            int b2 = t * 4 + k;
            if (b2 < NB) { gb[b2] = base + row[b2]; cnt[b2] = 0; }
            base += vals[k];
        }
        __syncthreads();
        int ebase = vb * BIN_TILE;
        int eend = min(ebase + BIN_TILE, E);
        for (int i = ebase + t; i < eend; i += 256) {
            int s = ei[i];
            int d = ei[E + i];
            int b = d >> BKT_SHIFT;
            int off = atomicAdd(&cnt[b], 1);
            stage[gb[b] + off] = ((unsigned int)(d & BKT_MASK) << 24) | (unsigned int)s;
        }
        __syncthreads();
    }
    grid.sync();

    // ---------------- P3: bsort (per-bucket counting sort) ----------------
    for (int vb = blockIdx.x; vb < NB; vb += nblk) {
        int* lout = smem;
        int* hist = smem + 14336;
        int* sc   = smem + 14592;
        int* rp   = smem + 14848;
        int* lc   = smem + 15104;
        int* part = smem + 15360;
        int* sbb  = smem + 15616;
        int node0 = vb << BKT_SHIFT;
        int nloc = min(256, N - node0);

        int vals[4]; int s0 = 0;
#pragma unroll
        for (int k = 0; k < 4; ++k) {
            int b2 = t * 4 + k;
            vals[k] = (b2 < NB) ? tot[b2] : 0;
            s0 += vals[k];
        }
        part[t] = s0;
        __syncthreads();
        for (int off = 1; off < 256; off <<= 1) {
            int u = (t >= off) ? part[t - off] : 0;
            __syncthreads();
            part[t] += u;
            __syncthreads();
        }
        int base = part[t] - s0;
#pragma unroll
        for (int k = 0; k < 4; ++k) {
            int b2 = t * 4 + k;
            if (b2 == vb) { sbb[0] = base; sbb[1] = base + vals[k]; }
            base += vals[k];
        }
        __syncthreads();
        const int bb = sbb[0], be = sbb[1];

        hist[t] = 0; lc[t] = 0;
        __syncthreads();
        for (int i = bb + t; i < be; i += 256)
            atomicAdd(&hist[stage[i] >> 24], 1);
        __syncthreads();
        sc[t] = hist[t];
        __syncthreads();
        for (int off = 1; off < 256; off <<= 1) {
            int u = (t >= off) ? sc[t - off] : 0;
            __syncthreads();
            sc[t] += u;
            __syncthreads();
        }
        int rpg = bb + sc[t] - hist[t];
        rp[t] = rpg;
        if (t < nloc) rowptr[node0 + t] = rpg;
        if (vb == 0 && t == 0) rowptr[N] = E;
        __syncthreads();
        for (int i = bb + t; i < be; i += 256) {
            unsigned int wrec = stage[i];
            int dl = (int)(wrec >> 24);
            int src = (int)(wrec & 0x00FFFFFFu);
            int pos = rp[dl] + atomicAdd(&lc[dl], 1);
            int rel = pos - bb;
            if (rel < BKT_CAP) lout[rel] = src;
            else csr[pos] = src;
        }
        __syncthreads();
        int cntb = be - bb; if (cntb > BKT_CAP) cntb = BKT_CAP;
        for (int i = t; i < cntb; i += 256) csr[bb + i] = lout[i];
        __syncthreads();
    }
}

// =================== launch 2: h = x@W^T via MFMA + att coeffs ===================
__global__ __launch_bounds__(256) void k_lin(const float* __restrict__ x,
                                             const unsigned short* __restrict__ wb,
                                             const float* __restrict__ att_s,
                                             const float* __restrict__ att_d,
                                             unsigned short* __restrict__ h2,
                                             float* __restrict__ asrc,
                                             float* __restrict__ adst, int N) {
    const int t = threadIdx.x;
    const int lane = t & 63;
    const int wid = t >> 6;
    const int row0 = (blockIdx.x * 4 + wid) * 16;
    const int rlo = lane & 15;       // A-row / B-col / C-col offset
    const int khi = lane >> 4;       // k-chunk / C-row-group

    int arow = row0 + rlo; if (arow >= N) arow = N - 1;   // clamp (stores guarded)
    const float* xrow = x + (long long)arow * 128;
    bf16x8 afrag[4];
#pragma unroll
    for (int ks = 0; ks < 4; ++ks) {
        int k0 = ks * 32 + khi * 8;
        float4 xa = *(const float4*)(xrow + k0);
        float4 xb = *(const float4*)(xrow + k0 + 4);
        bf16x8 a;
        a[0] = (short)f2bf(xa.x); a[1] = (short)f2bf(xa.y);
        a[2] = (short)f2bf(xa.z); a[3] = (short)f2bf(xa.w);
        a[4] = (short)f2bf(xb.x); a[5] = (short)f2bf(xb.y);
        a[6] = (short)f2bf(xb.z); a[7] = (short)f2bf(xb.w);
        afrag[ks] = a;
    }

    float ps0[4] = {0.f,0.f,0.f,0.f}, pd0[4] = {0.f,0.f,0.f,0.f};
    float ps1[4] = {0.f,0.f,0.f,0.f}, pd1[4] = {0.f,0.f,0.f,0.f};

    for (int ct = 0; ct < 8; ++ct) {             // 8 col-tiles of 16
        const int col = ct * 16 + rlo;
        f32x4 acc = {0.f, 0.f, 0.f, 0.f};
#pragma unroll
        for (int ks = 0; ks < 4; ++ks) {
            bf16x8 b = *(const bf16x8*)(wb + (size_t)col * 128 + ks * 32 + khi * 8);
            acc = __builtin_amdgcn_mfma_f32_16x16x32_bf16(afrag[ks], b, acc, 0, 0, 0);
        }
        const float as = att_s[col], ad = att_d[col];
        const bool head0 = (ct < 4);             // wave-uniform
#pragma unroll
        for (int r = 0; r < 4; ++r) {
            int row = row0 + khi * 4 + r;
            if (row < N) h2[(long long)row * 128 + col] = f2bf(acc[r]);
            float v = acc[r];
            if (head0) { ps0[r] = fmaf(v, as, ps0[r]); pd0[r] = fmaf(v, ad, pd0[r]); }
            else       { ps1[r] = fmaf(v, as, ps1[r]); pd1[r] = fmaf(v, ad, pd1[r]); }
        }
    }

#pragma unroll
    for (int off = 1; off <= 8; off <<= 1) {
#pragma unroll
        for (int r = 0; r < 4; ++r) {
            ps0[r] += __shfl_xor(ps0[r], off);
            pd0[r] += __shfl_xor(pd0[r], off);
            ps1[r] += __shfl_xor(ps1[r], off);
            pd1[r] += __shfl_xor(pd1[r], off);
        }
    }
    if (rlo == 0) {
#pragma unroll
        for (int r = 0; r < 4; ++r) {
            int row = row0 + khi * 4 + r;
            if (row < N) {
                asrc[row * 2]     = ps0[r];
                asrc[row * 2 + 1] = ps1[r];
                adst[row * 2]     = pd0[r];
                adst[row * 2 + 1] = pd1[r];
            }
        }
    }
}

// =================== launch 3: aggregation ===================
__global__ __launch_bounds__(256) void k_agg(const int* __restrict__ rowptr,
                                             const int* __restrict__ csr_src,
                                             const unsigned short* __restrict__ h2,
                                             const float* __restrict__ asrc,
                                             const float* __restrict__ adst,
                                             const float* __restrict__ bias,
                                             const int* __restrict__ batch,
                                             float* __restrict__ pooled, int N) {
    int n = __builtin_amdgcn_readfirstlane(blockIdx.x * 4 + (threadIdx.x >> 6));
    const int lane = threadIdx.x & 63;
    if (n >= N) return;
    const bool lo = (lane < 32);
    const int el = lane & 31;        // owned edge slot within 32-edge chunk

    float2 adn = *(const float2*)(adst + (size_t)n * 2);
    float2 asn = *(const float2*)(asrc + (size_t)n * 2);
    float e0 = asn.x + adn.x; e0 = e0 > 0.f ? e0 : 0.2f * e0;
    float e1 = asn.y + adn.y; e1 = e1 > 0.f ? e1 : 0.2f * e1;
    float w0 = __expf(e0), w1 = __expf(e1);   // self-loop weights

    // self-loop: lane owns dword `lane` of the row = channels 2lane, 2lane+1
    unsigned int v = ((const unsigned int*)(h2 + (size_t)n * 128))[lane];
    float wh = lo ? w0 : w1;
    float aX = wh * lo16(v), aY = wh * hi16(v);
    float ps = 0.f;                  // low lanes: head0 partial; high: head1
    const float adh = lo ? adn.x : adn.y;

    const int beg = rowptr[n], end = rowptr[n + 1];
    for (int base = beg; base < end; base += 32) {
        int cnt = min(32, end - base);
        // stage: lane el owns edge el; low half computes head0 exp, high head1
        int sv = n;
        if (el < cnt) sv = csr_src[base + el];            // coalesced
        float av = asrc[(size_t)sv * 2 + (lo ? 0 : 1)];   // 4B gather
        float f = av + adh; f = f > 0.f ? f : 0.2f * f;
        float usel = (el < cnt) ? __expf(f) : 0.f;
        ps += usel;

        int k = 0;
        for (; k + 8 <= cnt; k += 8) {
#pragma unroll
            for (int j = 0; j < 8; ++j) {
                int e = k + j;
                int se = __builtin_amdgcn_readlane(sv, e);        // SGPR
                float su0 = rlane_f(usel, e);                     // SGPR (head0)
                float su1 = rlane_f(usel, e + 32);                // SGPR (head1)
                float uu = lo ? su0 : su1;                        // cndmask
                unsigned int vv = ((const unsigned int*)(h2 + (size_t)se * 128))[lane];
                aX = fmaf(uu, lo16(vv), aX);
                aY = fmaf(uu, hi16(vv), aY);
            }
        }
        for (; k < cnt; ++k) {
            int se = __builtin_amdgcn_readlane(sv, k);
            float su0 = rlane_f(usel, k);
            float su1 = rlane_f(usel, k + 32);
            float uu = lo ? su0 : su1;
            unsigned int vv = ((const unsigned int*)(h2 + (size_t)se * 128))[lane];
            aX = fmaf(uu, lo16(vv), aX);
            aY = fmaf(uu, hi16(vv), aY);
        }
    }

    // softmax denominators: reduce within each 32-lane half
#pragma unroll
    for (int off = 1; off <= 16; off <<= 1)
        ps += __shfl_xor(ps, off);
    float sdiv = ps + (lo ? w0 : w1);

    int j0 = lane * 2;
    float2 bv = *(const float2*)(bias + j0);
    float o0 = aX / sdiv + bv.x;
    float o1 = aY / sdiv + bv.y;
    int g = batch[n];
    atomicAdd(&pooled[(size_t)g * 128 + j0], o0);
    atomicAdd(&pooled[(size_t)g * 128 + j0 + 1], o1);
}

// ====== launch 4: BN stats (redundant per block, G-way parallel) + FC ======
__global__ __launch_bounds__(128) void k_fcstat(const float* __restrict__ pooled,
                                                const float* __restrict__ gamma,
                                                const float* __restrict__ beta,
                                                const float* __restrict__ fcw,
                                                const float* __restrict__ fcb,
                                                float* __restrict__ out, int G, int LAT) {
    __shared__ float nrm[128];
    int t = threadIdx.x;           // channel
    float sum = 0.f, sq = 0.f;
#pragma unroll 8
    for (int g = 0; g < G; ++g) {
        float v = pooled[(size_t)g * 128 + t];
        sum += v; sq += v * v;
    }
    float mu = sum / (float)G;
    float var = sq / (float)G - mu * mu;
    float sc = gamma[t] * rsqrtf(var + 1e-5f);
    float sh = beta[t] - mu * sc;

    int g = blockIdx.x;
    nrm[t] = pooled[(size_t)g * 128 + t] * sc + sh;
    __syncthreads();
    if (t < LAT) {
        float acc = fcb[t];
#pragma unroll 8
        for (int j = 0; j < 128; ++j)
            acc = fmaf(nrm[j], fcw[t * 128 + j], acc);
        out[g * LAT + t] = acc;
    }
}

extern "C" void kernel_launch(void* const* d_in, const int* in_sizes, int n_in,
                              void* d_out, int out_size, void* d_ws, size_t ws_size,
                              hipStream_t stream) {
    const float* x     = (const float*)d_in[0];
    const int*   ei    = (const int*)d_in[1];
    const int*   batch = (const int*)d_in[2];
    const float* lin_w = (const float*)d_in[4];
    const float* att_s = (const float*)d_in[5];
    const float* att_d = (const float*)d_in[6];
    const float* bias  = (const float*)d_in[7];
    const float* gamma = (const float*)d_in[8];
    const float* beta  = (const float*)d_in[9];
    const float* fcw   = (const float*)d_in[10];
    const float* fcb   = (const float*)d_in[11];
    float* out = (float*)d_out;

    const int N   = in_sizes[2];
    const int E   = in_sizes[1] / 2;
    const int LAT = in_sizes[11];
    const int G   = out_size / LAT;
    const int NB  = (N + 255) >> BKT_SHIFT;
    const int nbin = (E + BIN_TILE - 1) / BIN_TILE;
    const int nlin = (N + 63) / 64;

    char* ws = (char*)d_ws;
    unsigned short* h2 = (unsigned short*)ws; ws += (size_t)N * 128 * 2;
    unsigned short* wb = (unsigned short*)ws; ws += (size_t)128 * 128 * 2;
    float* asrc   = (float*)ws; ws += (size_t)N * 2 * 4;
    float* adst   = (float*)ws; ws += (size_t)N * 2 * 4;
    float* pooled = (float*)ws; ws += (size_t)G * 128 * 4;   // zeroed in k_csr P0
    int*   tot    = (int*)ws;   ws += (size_t)NB * 4;
    int*   blkhist= (int*)ws;   ws += (size_t)nbin * NB * 4;
    int*   rowptr = (int*)ws;   ws += (size_t)(N + 1) * 4;
    unsigned int* stage = (unsigned int*)ws; ws += (size_t)E * 4;
    int*   csr    = (int*)ws;   ws += (size_t)E * 4;

    long long npool = (long long)G * 128;
    int E_ = E, NB_ = NB, nbin_ = nbin, N_ = N;
    void* cargs[] = {
        (void*)&ei, (void*)&E_, (void*)&blkhist, (void*)&NB_,
        (void*)&lin_w, (void*)&wb, (void*)&pooled, (void*)&npool,
        (void*)&nbin_, (void*)&tot, (void*)&rowptr, (void*)&csr,
        (void*)&stage, (void*)&N_
    };
    // grid = nbin (403): 62KB LDS -> 2 blocks/CU -> 512 co-resident capacity.
    hipLaunchCooperativeKernel((const void*)k_csr, dim3(nbin), dim3(256),
                               cargs, 0, stream);

    k_lin<<<nlin, 256, 0, stream>>>(x, wb, att_s, att_d, h2, asrc, adst, N);
    k_agg<<<(N + 3) / 4, 256, 0, stream>>>(rowptr, csr, h2, asrc, adst, bias, batch, pooled, N);
    k_fcstat<<<G, 128, 0, stream>>>(pooled, gamma, beta, fcw, fcb, out, G, LAT);
}

// Round 20
// 163.970 us; speedup vs baseline: 1.9974x; 1.9974x over previous
//
#include <hip/hip_runtime.h>
#include <hip/hip_bf16.h>

// GAT. 6-launch pipeline (R18-proven bodies; bnstat folded into fc):
//  1) k_histprep: dst bucket histograms || W fp32->bf16 || zero pooled
//  2) k_linscan: h = x@W^T via bf16 MFMA + fused att coeffs || wave-parallel
//     2D scan of block histograms (1 wave/bucket)
//  3) k_bin: scatter edges into bucket runs (LDS cursors, in-block base scan)
//  4) k_bsort: per-bucket counting sort -> rowptr + csr
//  5) k_agg: wave per dst, scalarized broadcasts (v_readlane -> SGPR),
//     coalesced 256B row gathers, zero DS in hot loop, fused graph pooling
//  6) k_fcstat: BN stats recomputed per block (G-way parallel) + FC
// H=2 x C=64.  Softmax max-shift skipped (|e| small, exp safe in fp32).
// Lessons: shfl under divergence = poison (R7); s_load in DS loops = lgkmcnt
// drains (R11); split-lane atomics = write amplification (R10); per-bucket
// global atomic cursors = contention (R4); single-block serialization =
// latency disaster (R14, R17); cooperative grid.sync across non-coherent
// XCD L2s = cache-flush stalls (R19) — keep phases as separate launches.

#define BKT_SHIFT 8              // 256 nodes per bucket
#define BKT_MASK  255
#define BKT_CAP   14336          // LDS staging records in k_bsort (56 KB)
#define BIN_TILE  4096           // edges per block in hist/k_bin

typedef __attribute__((ext_vector_type(8))) short bf16x8;
typedef __attribute__((ext_vector_type(4))) float f32x4;

static __device__ __forceinline__ float lo16(unsigned int u) {
    union { unsigned int i; float f; } c; c.i = u << 16; return c.f;
}
static __device__ __forceinline__ float hi16(unsigned int u) {
    union { unsigned int i; float f; } c; c.i = u & 0xffff0000u; return c.f;
}
static __device__ __forceinline__ unsigned short f2bf(float f) {
    unsigned int b = __builtin_bit_cast(unsigned int, f);
    return (unsigned short)((b >> 16) + ((b >> 15) & 1));
}
static __device__ __forceinline__ float rlane_f(float x, int l) {
    return __builtin_bit_cast(float, __builtin_amdgcn_readlane(__builtin_bit_cast(int, x), l));
}

// ---- launch 1: hist blocks [0,nbin) | wcvt blocks [nbin,nbin+64) |
//                pooled-zero blocks [nbin+64, nbin+128) ----
__global__ __launch_bounds__(256) void k_histprep(const int* __restrict__ ei, int E,
                                                  int* __restrict__ blkhist, int NB,
                                                  const float* __restrict__ w,
                                                  unsigned short* __restrict__ wb,
                                                  float* __restrict__ pooled,
                                                  long long npool, int nbin) {
    const int t = threadIdx.x;
    const int bid = blockIdx.x;
    if (bid < nbin) {
        __shared__ int cnt[1024];
        for (int i = t; i < 1024; i += 256) cnt[i] = 0;
        __syncthreads();
        int base = bid * BIN_TILE;
        int end = min(base + BIN_TILE, E);
        for (int i = base + t; i < end; i += 256)
            atomicAdd(&cnt[ei[E + i] >> BKT_SHIFT], 1);
        __syncthreads();
        int* row = blkhist + (size_t)bid * NB;
        for (int b = t; b < NB; b += 256) row[b] = cnt[b];
    } else if (bid < nbin + 64) {
        int i = (bid - nbin) * 256 + t;          // 64*256 = 16384 = 128*128
        wb[i] = f2bf(w[i]);
    } else {
        long long i = (long long)(bid - nbin - 64) * 256 + t;
        for (; i < npool; i += 64 * 256) pooled[i] = 0.f;
    }
}

// ---- launch 2: lin blocks [0,nlin) | scanA blocks [nlin, nlin+ceil(NB/4)) ----
__global__ __launch_bounds__(256) void k_linscan(const float* __restrict__ x,
                                                 const unsigned short* __restrict__ wb,
                                                 const float* __restrict__ att_s,
                                                 const float* __restrict__ att_d,
                                                 unsigned short* __restrict__ h2,
                                                 float* __restrict__ asrc,
                                                 float* __restrict__ adst, int N,
                                                 int* __restrict__ blkhist,
                                                 int* __restrict__ tot,
                                                 int NB, int nbin, int nlin) {
    const int t = threadIdx.x;
    if ((int)blockIdx.x >= nlin) {
        // ---------- scanA: wave-parallel scan over blocks (1 wave/bucket) ----
        int b = (blockIdx.x - nlin) * 4 + (t >> 6);
        int lane = t & 63;
        if (b >= NB) return;
        int run = 0;
        for (int blk0 = 0; blk0 < nbin; blk0 += 64) {
            int idx = blk0 + lane;
            int v = (idx < nbin) ? blkhist[(size_t)idx * NB + b] : 0;
            int inc = v;                     // wave inclusive scan (convergent)
#pragma unroll
            for (int off = 1; off < 64; off <<= 1) {
                int u = __shfl_up(inc, off);
                if (lane >= off) inc += u;
            }
            if (idx < nbin) blkhist[(size_t)idx * NB + b] = run + (inc - v);
            run += __shfl(inc, 63);          // chunk total broadcast
        }
        if (lane == 0) tot[b] = run;
        return;
    }
    // ---------- linear part: MFMA + fused attention coefficients ----------
    const int lane = t & 63;
    const int wid = t >> 6;
    const int row0 = (blockIdx.x * 4 + wid) * 16;
    const int rlo = lane & 15;       // A-row / B-col / C-col offset
    const int khi = lane >> 4;       // k-chunk / C-row-group

    int arow = row0 + rlo; if (arow >= N) arow = N - 1;   // clamp (stores guarded)
    const float* xrow = x + (long long)arow * 128;
    bf16x8 afrag[4];
#pragma unroll
    for (int ks = 0; ks < 4; ++ks) {
        int k0 = ks * 32 + khi * 8;
        float4 xa = *(const float4*)(xrow + k0);
        float4 xb = *(const float4*)(xrow + k0 + 4);
        bf16x8 a;
        a[0] = (short)f2bf(xa.x); a[1] = (short)f2bf(xa.y);
        a[2] = (short)f2bf(xa.z); a[3] = (short)f2bf(xa.w);
        a[4] = (short)f2bf(xb.x); a[5] = (short)f2bf(xb.y);
        a[6] = (short)f2bf(xb.z); a[7] = (short)f2bf(xb.w);
        afrag[ks] = a;
    }

    float ps0[4] = {0.f,0.f,0.f,0.f}, pd0[4] = {0.f,0.f,0.f,0.f};
    float ps1[4] = {0.f,0.f,0.f,0.f}, pd1[4] = {0.f,0.f,0.f,0.f};

    for (int ct = 0; ct < 8; ++ct) {             // 8 col-tiles of 16
        const int col = ct * 16 + rlo;
        f32x4 acc = {0.f, 0.f, 0.f, 0.f};
#pragma unroll
        for (int ks = 0; ks < 4; ++ks) {
            bf16x8 b = *(const bf16x8*)(wb + (size_t)col * 128 + ks * 32 + khi * 8);
            acc = __builtin_amdgcn_mfma_f32_16x16x32_bf16(afrag[ks], b, acc, 0, 0, 0);
        }
        const float as = att_s[col], ad = att_d[col];
        const bool head0 = (ct < 4);             // wave-uniform
#pragma unroll
        for (int r = 0; r < 4; ++r) {
            int row = row0 + khi * 4 + r;
            if (row < N) h2[(long long)row * 128 + col] = f2bf(acc[r]);
            float v = acc[r];
            if (head0) { ps0[r] = fmaf(v, as, ps0[r]); pd0[r] = fmaf(v, ad, pd0[r]); }
            else       { ps1[r] = fmaf(v, as, ps1[r]); pd1[r] = fmaf(v, ad, pd1[r]); }
        }
    }

#pragma unroll
    for (int off = 1; off <= 8; off <<= 1) {
#pragma unroll
        for (int r = 0; r < 4; ++r) {
            ps0[r] += __shfl_xor(ps0[r], off);
            pd0[r] += __shfl_xor(pd0[r], off);
            ps1[r] += __shfl_xor(ps1[r], off);
            pd1[r] += __shfl_xor(pd1[r], off);
        }
    }
    if (rlo == 0) {
#pragma unroll
        for (int r = 0; r < 4; ++r) {
            int row = row0 + khi * 4 + r;
            if (row < N) {
                asrc[row * 2]     = ps0[r];
                asrc[row * 2 + 1] = ps1[r];
                adst[row * 2]     = pd0[r];
                adst[row * 2 + 1] = pd1[r];
            }
        }
    }
}

// ------- CSR build C: scatter with LDS cursors; bucket bases recomputed
//         in-block from tot (256-thread 4-way scan) -------
__global__ __launch_bounds__(256) void k_bin(const int* __restrict__ ei, int E,
                                             const int* __restrict__ blkhist,
                                             const int* __restrict__ tot,
                                             unsigned int* __restrict__ stage, int NB) {
    __shared__ int gb[1024];
    __shared__ int cnt[1024];
    __shared__ int part[256];
    int t = threadIdx.x;
    const int* row = blkhist + (size_t)blockIdx.x * NB;
    int vals[4]; int s0 = 0;
#pragma unroll
    for (int k = 0; k < 4; ++k) {
        int b2 = t * 4 + k;
        vals[k] = (b2 < NB) ? tot[b2] : 0;
        s0 += vals[k];
    }
    part[t] = s0;
    __syncthreads();
    for (int off = 1; off < 256; off <<= 1) {
        int u = (t >= off) ? part[t - off] : 0;
        __syncthreads();
        part[t] += u;
        __syncthreads();
    }
    int base = part[t] - s0;
#pragma unroll
    for (int k = 0; k < 4; ++k) {
        int b2 = t * 4 + k;
        if (b2 < NB) { gb[b2] = base + row[b2]; cnt[b2] = 0; }
        base += vals[k];
    }
    __syncthreads();
    int ebase = blockIdx.x * BIN_TILE;
    int eend = min(ebase + BIN_TILE, E);
    for (int i = ebase + t; i < eend; i += 256) {
        int s = ei[i];
        int d = ei[E + i];
        int b = d >> BKT_SHIFT;
        int off = atomicAdd(&cnt[b], 1);
        stage[gb[b] + off] = ((unsigned int)(d & BKT_MASK) << 24) | (unsigned int)s;
    }
}

// ------- CSR build D: per-bucket counting sort; bucket base recomputed
//         in-block from tot; emits rowptr AND csr -------
__global__ __launch_bounds__(256) void k_bsort(const int* __restrict__ tot,
                                               const unsigned int* __restrict__ stage,
                                               int* __restrict__ rowptr,
                                               int* __restrict__ csr,
                                               int N, int E, int NB) {
    __shared__ int hist[256];
    __shared__ int sc[256];
    __shared__ int rp[256];
    __shared__ int lc[256];
    __shared__ int part[256];
    __shared__ int s_bb, s_be;
    __shared__ int lout[BKT_CAP];
    int b = blockIdx.x;
    int node0 = b << BKT_SHIFT;
    int nloc = min(256, N - node0);
    int t = threadIdx.x;

    // phase 0: bucket base = exclusive prefix of tot up to b
    int vals[4]; int s0 = 0;
#pragma unroll
    for (int k = 0; k < 4; ++k) {
        int b2 = t * 4 + k;
        vals[k] = (b2 < NB) ? tot[b2] : 0;
        s0 += vals[k];
    }
    part[t] = s0;
    __syncthreads();
    for (int off = 1; off < 256; off <<= 1) {
        int u = (t >= off) ? part[t - off] : 0;
        __syncthreads();
        part[t] += u;
        __syncthreads();
    }
    int base = part[t] - s0;
#pragma unroll
    for (int k = 0; k < 4; ++k) {
        int b2 = t * 4 + k;
        if (b2 == b) { s_bb = base; s_be = base + vals[k]; }
        base += vals[k];
    }
    __syncthreads();
    const int bb = s_bb, be = s_be;

    hist[t] = 0; lc[t] = 0;
    __syncthreads();
    for (int i = bb + t; i < be; i += 256)
        atomicAdd(&hist[stage[i] >> 24], 1);
    __syncthreads();
    sc[t] = hist[t];
    __syncthreads();
    for (int off = 1; off < 256; off <<= 1) {
        int u = (t >= off) ? sc[t - off] : 0;
        __syncthreads();
        sc[t] += u;
        __syncthreads();
    }
    int rpg = bb + sc[t] - hist[t];
    rp[t] = rpg;
    if (t < nloc) rowptr[node0 + t] = rpg;
    if (b == 0 && t == 0) rowptr[N] = E;
    __syncthreads();
    for (int i = bb + t; i < be; i += 256) {
        unsigned int wrec = stage[i];
        int dl = (int)(wrec >> 24);
        int src = (int)(wrec & 0x00FFFFFFu);
        int pos = rp[dl] + atomicAdd(&lc[dl], 1);
        int rel = pos - bb;
        if (rel < BKT_CAP) lout[rel] = src;
        else csr[pos] = src;
    }
    __syncthreads();
    int cntb = be - bb; if (cntb > BKT_CAP) cntb = BKT_CAP;
    for (int i = t; i < cntb; i += 256) csr[bb + i] = lout[i];
}

// ------- aggregation: wave per dst; scalarized broadcasts (readlane/SALU);
//         coalesced 256B row gathers; zero DS in hot loop -------
__global__ __launch_bounds__(256) void k_agg(const int* __restrict__ rowptr,
                                             const int* __restrict__ csr_src,
                                             const unsigned short* __restrict__ h2,
                                             const float* __restrict__ asrc,
                                             const float* __restrict__ adst,
                                             const float* __restrict__ bias,
                                             const int* __restrict__ batch,
                                             float* __restrict__ pooled, int N) {
    int n = __builtin_amdgcn_readfirstlane(blockIdx.x * 4 + (threadIdx.x >> 6));
    const int lane = threadIdx.x & 63;
    if (n >= N) return;
    const bool lo = (lane < 32);
    const int el = lane & 31;        // owned edge slot within 32-edge chunk

    float2 adn = *(const float2*)(adst + (size_t)n * 2);
    float2 asn = *(const float2*)(asrc + (size_t)n * 2);
    float e0 = asn.x + adn.x; e0 = e0 > 0.f ? e0 : 0.2f * e0;
    float e1 = asn.y + adn.y; e1 = e1 > 0.f ? e1 : 0.2f * e1;
    float w0 = __expf(e0), w1 = __expf(e1);   // self-loop weights

    // self-loop: lane owns dword `lane` of the row = channels 2lane, 2lane+1
    unsigned int v = ((const unsigned int*)(h2 + (size_t)n * 128))[lane];
    float wh = lo ? w0 : w1;
    float aX = wh * lo16(v), aY = wh * hi16(v);
    float ps = 0.f;                  // low lanes: head0 partial; high: head1
    const float adh = lo ? adn.x : adn.y;

    const int beg = rowptr[n], end = rowptr[n + 1];
    for (int base = beg; base < end; base += 32) {
        int cnt = min(32, end - base);
        // stage: lane el owns edge el; low half computes head0 exp, high head1
        int sv = n;
        if (el < cnt) sv = csr_src[base + el];            // coalesced
        float av = asrc[(size_t)sv * 2 + (lo ? 0 : 1)];   // 4B gather
        float f = av + adh; f = f > 0.f ? f : 0.2f * f;
        float usel = (el < cnt) ? __expf(f) : 0.f;
        ps += usel;

        int k = 0;
        for (; k + 8 <= cnt; k += 8) {
#pragma unroll
            for (int j = 0; j < 8; ++j) {
                int e = k + j;
                int se = __builtin_amdgcn_readlane(sv, e);        // SGPR
                float su0 = rlane_f(usel, e);                     // SGPR (head0)
                float su1 = rlane_f(usel, e + 32);                // SGPR (head1)
                float uu = lo ? su0 : su1;                        // cndmask
                unsigned int vv = ((const unsigned int*)(h2 + (size_t)se * 128))[lane];
                aX = fmaf(uu, lo16(vv), aX);
                aY = fmaf(uu, hi16(vv), aY);
            }
        }
        for (; k < cnt; ++k) {
            int se = __builtin_amdgcn_readlane(sv, k);
            float su0 = rlane_f(usel, k);
            float su1 = rlane_f(usel, k + 32);
            float uu = lo ? su0 : su1;
            unsigned int vv = ((const unsigned int*)(h2 + (size_t)se * 128))[lane];
            aX = fmaf(uu, lo16(vv), aX);
            aY = fmaf(uu, hi16(vv), aY);
        }
    }

    // softmax denominators: reduce within each 32-lane half
#pragma unroll
    for (int off = 1; off <= 16; off <<= 1)
        ps += __shfl_xor(ps, off);
    float sdiv = ps + (lo ? w0 : w1);

    int j0 = lane * 2;
    float2 bv = *(const float2*)(bias + j0);
    float o0 = aX / sdiv + bv.x;
    float o1 = aY / sdiv + bv.y;
    int g = batch[n];
    atomicAdd(&pooled[(size_t)g * 128 + j0], o0);
    atomicAdd(&pooled[(size_t)g * 128 + j0 + 1], o1);
}

// ====== launch 6: BN stats (redundant per block, G-way parallel) + FC ======
__global__ __launch_bounds__(128) void k_fcstat(const float* __restrict__ pooled,
                                                const float* __restrict__ gamma,
                                                const float* __restrict__ beta,
                                                const float* __restrict__ fcw,
                                                const float* __restrict__ fcb,
                                                float* __restrict__ out, int G, int LAT) {
    __shared__ float nrm[128];
    int t = threadIdx.x;           // channel
    float sum = 0.f, sq = 0.f;
#pragma unroll 8
    for (int g = 0; g < G; ++g) {
        float v = pooled[(size_t)g * 128 + t];
        sum += v; sq += v * v;
    }
    float mu = sum / (float)G;
    float var = sq / (float)G - mu * mu;
    float sc = gamma[t] * rsqrtf(var + 1e-5f);
    float sh = beta[t] - mu * sc;

    int g = blockIdx.x;
    nrm[t] = pooled[(size_t)g * 128 + t] * sc + sh;
    __syncthreads();
    if (t < LAT) {
        float acc = fcb[t];
#pragma unroll 8
        for (int j = 0; j < 128; ++j)
            acc = fmaf(nrm[j], fcw[t * 128 + j], acc);
        out[g * LAT + t] = acc;
    }
}

extern "C" void kernel_launch(void* const* d_in, const int* in_sizes, int n_in,
                              void* d_out, int out_size, void* d_ws, size_t ws_size,
                              hipStream_t stream) {
    const float* x     = (const float*)d_in[0];
    const int*   ei    = (const int*)d_in[1];
    const int*   batch = (const int*)d_in[2];
    const float* lin_w = (const float*)d_in[4];
    const float* att_s = (const float*)d_in[5];
    const float* att_d = (const float*)d_in[6];
    const float* bias  = (const float*)d_in[7];
    const float* gamma = (const float*)d_in[8];
    const float* beta  = (const float*)d_in[9];
    const float* fcw   = (const float*)d_in[10];
    const float* fcb   = (const float*)d_in[11];
    float* out = (float*)d_out;

    const int N   = in_sizes[2];
    const int E   = in_sizes[1] / 2;
    const int LAT = in_sizes[11];
    const int G   = out_size / LAT;
    const int NB  = (N + 255) >> BKT_SHIFT;
    const int nbin = (E + BIN_TILE - 1) / BIN_TILE;
    const int nlin = (N + 63) / 64;

    char* ws = (char*)d_ws;
    unsigned short* h2 = (unsigned short*)ws; ws += (size_t)N * 128 * 2;
    unsigned short* wb = (unsigned short*)ws; ws += (size_t)128 * 128 * 2;
    float* asrc   = (float*)ws; ws += (size_t)N * 2 * 4;
    float* adst   = (float*)ws; ws += (size_t)N * 2 * 4;
    float* pooled = (float*)ws; ws += (size_t)G * 128 * 4;   // zeroed in launch 1
    int*   tot    = (int*)ws;   ws += (size_t)NB * 4;
    int*   blkhist= (int*)ws;   ws += (size_t)nbin * NB * 4;
    int*   rowptr = (int*)ws;   ws += (size_t)(N + 1) * 4;
    unsigned int* stage = (unsigned int*)ws; ws += (size_t)E * 4;
    int*   csr    = (int*)ws;   ws += (size_t)E * 4;

    k_histprep<<<nbin + 128, 256, 0, stream>>>(ei, E, blkhist, NB, lin_w, wb,
                                               pooled, (long long)G * 128, nbin);
    k_linscan<<<nlin + (NB + 3) / 4, 256, 0, stream>>>(x, wb, att_s, att_d, h2,
                                                       asrc, adst, N, blkhist, tot,
                                                       NB, nbin, nlin);
    k_bin<<<nbin, 256, 0, stream>>>(ei, E, blkhist, tot, stage, NB);
    k_bsort<<<NB, 256, 0, stream>>>(tot, stage, rowptr, csr, N, E, NB);
    k_agg<<<(N + 3) / 4, 256, 0, stream>>>(rowptr, csr, h2, asrc, adst, bias, batch, pooled, N);
    k_fcstat<<<G, 128, 0, stream>>>(pooled, gamma, beta, fcw, fcb, out, G, LAT);
}